// Round 1
// baseline (2071.478 us; speedup 1.0000x reference)
//
#include <hip/hip_runtime.h>
#include <hip/hip_bf16.h>

// GNN classifier: 2x GCNConv + global_mean_pool + 2-layer MLP.
// Baseline: atomic-scatter aggregation. Self-loops folded into epilogue.

#define NNODES 100000
#define NEDGES 3200000
#define NGRAPHS 256

// ---------------- degree ----------------
__global__ __launch_bounds__(256) void deg_kernel(const int* __restrict__ dst,
                                                  int* __restrict__ deg, int E) {
  int e = blockIdx.x * 256 + threadIdx.x;
  if (e < E) atomicAdd(&deg[dst[e]], 1);
}

__global__ __launch_bounds__(256) void dis_kernel(float* __restrict__ buf, int N) {
  int i = blockIdx.x * 256 + threadIdx.x;
  if (i < N) {
    int cnt = ((const int*)buf)[i];          // buffer currently holds int counts
    buf[i] = rsqrtf((float)(cnt + 1));       // +1 self-loop; deg >= 1 always
  }
}

// ---------------- dense GEMM: Y[n,64] = X[n,K] @ W[K,64] ----------------
template <int K>
__global__ __launch_bounds__(256) void gemm_k(const float* __restrict__ X,
                                              const float* __restrict__ W,
                                              float* __restrict__ Y, int nrows) {
  __shared__ float ws[K][64];
  __shared__ float xs[16][K];
  int t = threadIdx.x;

  // stage W (K*64 floats) via float4
  const float4* W4 = (const float4*)W;
  float4* ws4 = (float4*)(&ws[0][0]);
  constexpr int WV = K * 64 / 4;
  for (int i = t; i < WV; i += 256) ws4[i] = W4[i];

  int row0 = blockIdx.x * 16;
  int nr = min(16, nrows - row0);
  const float4* X4 = (const float4*)(X + (size_t)row0 * K);
  float4* xs4 = (float4*)(&xs[0][0]);
  for (int i = t; i < nr * K / 4; i += 256) xs4[i] = X4[i];
  __syncthreads();

  int wave = t >> 6, lane = t & 63;
  for (int r = wave; r < nr; r += 4) {
    float acc = 0.f;
#pragma unroll
    for (int k = 0; k < K; k += 4) {
      acc += xs[r][k + 0] * ws[k + 0][lane];
      acc += xs[r][k + 1] * ws[k + 1][lane];
      acc += xs[r][k + 2] * ws[k + 2][lane];
      acc += xs[r][k + 3] * ws[k + 3][lane];
    }
    Y[(size_t)(row0 + r) * 64 + lane] = acc;
  }
}

// ---------------- edge scatter: out[dst] += dis[src]*dis[dst] * xw[src] ----------------
__global__ __launch_bounds__(256) void scatter_kernel(const int* __restrict__ src,
                                                      const int* __restrict__ dst,
                                                      const float* __restrict__ dis,
                                                      const float* __restrict__ xw,
                                                      float* __restrict__ out, int E) {
  int lane = threadIdx.x & 63;
  int wave = blockIdx.x * 4 + (threadIdx.x >> 6);
  int nw = gridDim.x * 4;
  for (int e = wave; e < E; e += nw) {
    int s = src[e];
    int d = dst[e];
    float norm = dis[s] * dis[d];
    float v = norm * xw[(size_t)s * 64 + lane];
    atomicAdd(&out[(size_t)d * 64 + lane], v);
  }
}

// ---------------- conv1 epilogue: h = relu(acc + dis^2*xw + b) ----------------
__global__ __launch_bounds__(256) void finish1_kernel(float* __restrict__ h,
                                                      const float* __restrict__ xw,
                                                      const float* __restrict__ dis,
                                                      const float* __restrict__ b, int N) {
  size_t idx = (size_t)blockIdx.x * 256 + threadIdx.x;
  if (idx < (size_t)N * 64) {
    int node = (int)(idx >> 6), f = (int)(idx & 63);
    float di = dis[node];
    float v = h[idx] + di * di * xw[idx] + b[f];
    h[idx] = fmaxf(v, 0.f);
  }
}

// ---------------- conv2 epilogue + pooling atomics ----------------
__global__ __launch_bounds__(256) void finish2_pool_kernel(const float* __restrict__ hacc,
                                                           const float* __restrict__ xw,
                                                           const float* __restrict__ dis,
                                                           const float* __restrict__ b,
                                                           const int* __restrict__ batch,
                                                           float* __restrict__ psum,
                                                           float* __restrict__ pcnt, int N) {
  size_t idx = (size_t)blockIdx.x * 256 + threadIdx.x;
  if (idx < (size_t)N * 64) {
    int node = (int)(idx >> 6), f = (int)(idx & 63);
    float di = dis[node];
    float v = hacc[idx] + di * di * xw[idx] + b[f];
    int g = batch[node];
    atomicAdd(&psum[g * 64 + f], v);
    if (f == 0) atomicAdd(&pcnt[g], 1.0f);
  }
}

// ---------------- per-graph MLP ----------------
__global__ __launch_bounds__(64) void mlp_kernel(const float* __restrict__ psum,
                                                 const float* __restrict__ pcnt,
                                                 const float* __restrict__ Wf1,
                                                 const float* __restrict__ bf1,
                                                 const float* __restrict__ Wf2,
                                                 const float* __restrict__ bf2,
                                                 float* __restrict__ out) {
  int g = blockIdx.x;
  int lane = threadIdx.x;
  __shared__ float p[64];
  __shared__ float hh[32];
  float cnt = fmaxf(pcnt[g], 1.f);
  p[lane] = psum[g * 64 + lane] / cnt;
  __syncthreads();
  if (lane < 32) {
    float a = bf1[lane];
#pragma unroll
    for (int f = 0; f < 64; ++f) a += p[f] * Wf1[f * 32 + lane];
    hh[lane] = fmaxf(a, 0.f);
  }
  __syncthreads();
  if (lane < 8) {
    float a = bf2[lane];
#pragma unroll
    for (int j = 0; j < 32; ++j) a += hh[j] * Wf2[j * 8 + lane];
    out[g * 8 + lane] = a;
  }
}

extern "C" void kernel_launch(void* const* d_in, const int* in_sizes, int n_in,
                              void* d_out, int out_size, void* d_ws, size_t ws_size,
                              hipStream_t stream) {
  const float* x     = (const float*)d_in[0];
  const int*   ei    = (const int*)d_in[1];   // int64 in source, int32 on device (JAX x64 off)
  const int*   batch = (const int*)d_in[2];
  const float* W1  = (const float*)d_in[3];
  const float* b1  = (const float*)d_in[4];
  const float* W2  = (const float*)d_in[5];
  const float* b2  = (const float*)d_in[6];
  const float* Wf1 = (const float*)d_in[7];
  const float* bf1 = (const float*)d_in[8];
  const float* Wf2 = (const float*)d_in[9];
  const float* bf2 = (const float*)d_in[10];
  float* out = (float*)d_out;

  const int N = in_sizes[0] / 128;   // 100000
  const int E = in_sizes[1] / 2;     // 3200000
  const int* src = ei;
  const int* dst = ei + E;

  float* ws   = (float*)d_ws;
  float* xwA  = ws;                    // N*64 floats
  float* hB   = ws + (size_t)N * 64;   // N*64 floats
  float* dis  = hB + (size_t)N * 64;   // N floats (int deg first, then dis)
  float* psum = dis + N;               // NGRAPHS*64
  float* pcnt = psum + NGRAPHS * 64;   // NGRAPHS

  const size_t hbytes = (size_t)N * 64 * sizeof(float);

  // degree -> dis
  hipMemsetAsync(dis, 0, (size_t)N * sizeof(float), stream);
  deg_kernel<<<(E + 255) / 256, 256, 0, stream>>>(dst, (int*)dis, E);
  dis_kernel<<<(N + 255) / 256, 256, 0, stream>>>(dis, N);

  // conv1: xw1 = x@W1 ; scatter ; epilogue(relu)
  gemm_k<128><<<(N + 15) / 16, 256, 0, stream>>>(x, W1, xwA, N);
  hipMemsetAsync(hB, 0, hbytes, stream);
  scatter_kernel<<<2048, 256, 0, stream>>>(src, dst, dis, xwA, hB, E);
  finish1_kernel<<<(int)(((size_t)N * 64 + 255) / 256), 256, 0, stream>>>(hB, xwA, dis, b1, N);

  // conv2: xw2 = h1@W2 ; scatter ; epilogue + pool
  gemm_k<64><<<(N + 15) / 16, 256, 0, stream>>>(hB, W2, xwA, N);
  hipMemsetAsync(hB, 0, hbytes, stream);
  scatter_kernel<<<2048, 256, 0, stream>>>(src, dst, dis, xwA, hB, E);
  hipMemsetAsync(psum, 0, (NGRAPHS * 64 + NGRAPHS) * sizeof(float), stream);
  finish2_pool_kernel<<<(int)(((size_t)N * 64 + 255) / 256), 256, 0, stream>>>(
      hB, xwA, dis, b2, batch, psum, pcnt, N);

  // MLP head
  mlp_kernel<<<NGRAPHS, 64, 0, stream>>>(psum, pcnt, Wf1, bf1, Wf2, bf2, out);
}

// Round 2
// 1334.433 us; speedup vs baseline: 1.5523x; 1.5523x over previous
//
#include <hip/hip_runtime.h>
#include <hip/hip_bf16.h>

// GNN classifier: 2x GCNConv + global_mean_pool + 2-layer MLP.
// R1: CSR-gather aggregation (no float atomics). CSR built per call:
//   histogram(dst) -> 3-kernel exclusive scan -> fill (src,norm) sorted by dst.
// Gather: 1 wave per dst node, 64 lanes = 64 features; self-loop/bias/relu/pool fused.

#define NGRAPHS 256

// ---------------- histogram of dst ----------------
__global__ __launch_bounds__(256) void hist_kernel(const int* __restrict__ dst,
                                                   int* __restrict__ deg, int E) {
  int stride = gridDim.x * 256;
  for (int e = blockIdx.x * 256 + threadIdx.x; e < E; e += stride)
    atomicAdd(&deg[dst[e]], 1);
}

// ---------------- scan stage 1: per-1024-block sums ----------------
__global__ __launch_bounds__(256) void scan1_kernel(const int* __restrict__ deg,
                                                    int* __restrict__ bsum, int N) {
  __shared__ int red[4];
  int t = threadIdx.x;
  int base = blockIdx.x * 1024;
  int s = 0;
  for (int i = t; i < 1024; i += 256) {
    int idx = base + i;
    if (idx < N) s += deg[idx];
  }
#pragma unroll
  for (int o = 32; o > 0; o >>= 1) s += __shfl_down(s, o);
  if ((t & 63) == 0) red[t >> 6] = s;
  __syncthreads();
  if (t == 0) bsum[blockIdx.x] = red[0] + red[1] + red[2] + red[3];
}

// ---------------- scan stage 2: exclusive scan of <=128 block sums ----------------
__global__ __launch_bounds__(64) void scan2_kernel(int* __restrict__ bsum, int nb) {
  int lane = threadIdx.x;
  int v0 = lane < nb ? bsum[lane] : 0;
  int v1 = (64 + lane) < nb ? bsum[64 + lane] : 0;
  int x0 = v0, x1 = v1;
#pragma unroll
  for (int o = 1; o < 64; o <<= 1) {
    int y = __shfl_up(x0, o);
    if (lane >= o) x0 += y;
  }
#pragma unroll
  for (int o = 1; o < 64; o <<= 1) {
    int y = __shfl_up(x1, o);
    if (lane >= o) x1 += y;
  }
  int tot0 = __shfl(x0, 63);
  if (lane < nb) bsum[lane] = x0 - v0;
  if ((64 + lane) < nb) bsum[64 + lane] = tot0 + x1 - v1;
}

// ---------------- scan stage 3: per-element exclusive offsets + dis ----------------
__global__ __launch_bounds__(256) void scan3_kernel(const int* __restrict__ deg,
                                                    const int* __restrict__ bsum,
                                                    int* __restrict__ offs,
                                                    float* __restrict__ dis, int N) {
  __shared__ int wtot[4];
  int t = threadIdx.x, lane = t & 63, w = t >> 6;
  int base = blockIdx.x * 1024 + t * 4;
  int d0 = (base + 0) < N ? deg[base + 0] : 0;
  int d1 = (base + 1) < N ? deg[base + 1] : 0;
  int d2 = (base + 2) < N ? deg[base + 2] : 0;
  int d3 = (base + 3) < N ? deg[base + 3] : 0;
  int ts = d0 + d1 + d2 + d3;
  int x = ts;
#pragma unroll
  for (int o = 1; o < 64; o <<= 1) {
    int y = __shfl_up(x, o);
    if (lane >= o) x += y;
  }
  if (lane == 63) wtot[w] = x;
  __syncthreads();
  int woff = 0;
  for (int i = 0; i < w; ++i) woff += wtot[i];
  int o0 = bsum[blockIdx.x] + woff + (x - ts);
  int o1 = o0 + d0, o2 = o1 + d1, o3 = o2 + d2;
  if (base + 0 < N) { offs[base + 0] = o0; dis[base + 0] = rsqrtf((float)(d0 + 1)); }
  if (base + 1 < N) { offs[base + 1] = o1; dis[base + 1] = rsqrtf((float)(d1 + 1)); }
  if (base + 2 < N) { offs[base + 2] = o2; dis[base + 2] = rsqrtf((float)(d2 + 1)); }
  if (base + 3 < N) { offs[base + 3] = o3; dis[base + 3] = rsqrtf((float)(d3 + 1)); }
  if (base + 0 == N - 1) offs[N] = o0 + d0;
  if (base + 1 == N - 1) offs[N] = o1 + d1;
  if (base + 2 == N - 1) offs[N] = o2 + d2;
  if (base + 3 == N - 1) offs[N] = o3 + d3;
}

// ---------------- fill: edata[pos] = (src, norm) grouped by dst ----------------
__global__ __launch_bounds__(256) void fill_kernel(const int* __restrict__ src,
                                                   const int* __restrict__ dst,
                                                   const float* __restrict__ dis,
                                                   const int* __restrict__ offs,
                                                   int* __restrict__ cur,
                                                   int2* __restrict__ edata, int E) {
  int stride = gridDim.x * 256;
  for (int e = blockIdx.x * 256 + threadIdx.x; e < E; e += stride) {
    int s = src[e];
    int d = dst[e];
    float nm = dis[s] * dis[d];
    int pos = offs[d] + atomicAdd(&cur[d], 1);
    edata[pos] = make_int2(s, __float_as_int(nm));
  }
}

// ---------------- dense GEMM: Y[n,64] = X[n,K] @ W[K,64] ----------------
template <int K>
__global__ __launch_bounds__(256) void gemm_k(const float* __restrict__ X,
                                              const float* __restrict__ W,
                                              float* __restrict__ Y, int nrows) {
  __shared__ float ws[K][64];
  __shared__ float xs[16][K];
  int t = threadIdx.x;

  const float4* W4 = (const float4*)W;
  float4* ws4 = (float4*)(&ws[0][0]);
  constexpr int WV = K * 64 / 4;
  for (int i = t; i < WV; i += 256) ws4[i] = W4[i];

  int row0 = blockIdx.x * 16;
  int nr = min(16, nrows - row0);
  const float4* X4 = (const float4*)(X + (size_t)row0 * K);
  float4* xs4 = (float4*)(&xs[0][0]);
  for (int i = t; i < nr * K / 4; i += 256) xs4[i] = X4[i];
  __syncthreads();

  int wave = t >> 6, lane = t & 63;
  for (int r = wave; r < nr; r += 4) {
    float acc = 0.f;
#pragma unroll
    for (int k = 0; k < K; k += 4) {
      acc += xs[r][k + 0] * ws[k + 0][lane];
      acc += xs[r][k + 1] * ws[k + 1][lane];
      acc += xs[r][k + 2] * ws[k + 2][lane];
      acc += xs[r][k + 3] * ws[k + 3][lane];
    }
    Y[(size_t)(row0 + r) * 64 + lane] = acc;
  }
}

// ---------------- gather conv: one wave per dst node ----------------
// acc = sum_{e in CSR[n]} norm_e * xw[src_e] + dis[n]^2 * xw[n] + bias
// POOL=false: write relu(acc) to outbuf. POOL=true: atomically pool acc.
template <bool POOL>
__global__ __launch_bounds__(256) void gather_kernel(const int2* __restrict__ edata,
                                                     const int* __restrict__ offs,
                                                     const float* __restrict__ dis,
                                                     const float* __restrict__ xw,
                                                     const float* __restrict__ bias,
                                                     const int* __restrict__ batch,
                                                     float* __restrict__ outbuf,
                                                     float* __restrict__ psum,
                                                     float* __restrict__ pcnt, int N) {
  int lane = threadIdx.x & 63;
  int node = blockIdx.x * 4 + (threadIdx.x >> 6);
  if (node >= N) return;
  int beg = offs[node], end = offs[node + 1];
  float di = dis[node];
  float acc = di * di * xw[(size_t)node * 64 + lane];
  for (int j = beg; j < end; ++j) {
    int2 ed = edata[j];  // wave-uniform address -> HW broadcast
    float v = xw[(size_t)ed.x * 64 + lane];
    acc = fmaf(__int_as_float(ed.y), v, acc);
  }
  acc += bias[lane];
  if (POOL) {
    int g = batch[node];
    atomicAdd(&psum[g * 64 + lane], acc);
    if (lane == 0) atomicAdd(&pcnt[g], 1.0f);
  } else {
    outbuf[(size_t)node * 64 + lane] = fmaxf(acc, 0.f);
  }
}

// ---------------- per-graph MLP ----------------
__global__ __launch_bounds__(64) void mlp_kernel(const float* __restrict__ psum,
                                                 const float* __restrict__ pcnt,
                                                 const float* __restrict__ Wf1,
                                                 const float* __restrict__ bf1,
                                                 const float* __restrict__ Wf2,
                                                 const float* __restrict__ bf2,
                                                 float* __restrict__ out) {
  int g = blockIdx.x;
  int lane = threadIdx.x;
  __shared__ float p[64];
  __shared__ float hh[32];
  float cnt = fmaxf(pcnt[g], 1.f);
  p[lane] = psum[g * 64 + lane] / cnt;
  __syncthreads();
  if (lane < 32) {
    float a = bf1[lane];
#pragma unroll
    for (int f = 0; f < 64; ++f) a += p[f] * Wf1[f * 32 + lane];
    hh[lane] = fmaxf(a, 0.f);
  }
  __syncthreads();
  if (lane < 8) {
    float a = bf2[lane];
#pragma unroll
    for (int j = 0; j < 32; ++j) a += hh[j] * Wf2[j * 8 + lane];
    out[g * 8 + lane] = a;
  }
}

extern "C" void kernel_launch(void* const* d_in, const int* in_sizes, int n_in,
                              void* d_out, int out_size, void* d_ws, size_t ws_size,
                              hipStream_t stream) {
  const float* x     = (const float*)d_in[0];
  const int*   ei    = (const int*)d_in[1];  // int64 in source -> int32 on device (JAX x64 off)
  const int*   batch = (const int*)d_in[2];
  const float* W1  = (const float*)d_in[3];
  const float* b1  = (const float*)d_in[4];
  const float* W2  = (const float*)d_in[5];
  const float* b2  = (const float*)d_in[6];
  const float* Wf1 = (const float*)d_in[7];
  const float* bf1 = (const float*)d_in[8];
  const float* Wf2 = (const float*)d_in[9];
  const float* bf2 = (const float*)d_in[10];
  float* out = (float*)d_out;

  const int N = in_sizes[0] / 128;  // 100000
  const int E = in_sizes[1] / 2;    // 3200000
  const int* src = ei;
  const int* dst = ei + E;
  const int nb = (N + 1023) / 1024;  // scan blocks (98)

  // workspace layout (all 4B types; edata first for 8B alignment)
  int2*  edata = (int2*)d_ws;                      // E int2          (25.6 MB)
  float* xwA   = (float*)(edata + E);              // N*64 f          (25.6 MB)
  float* hB    = xwA + (size_t)N * 64;             // N*64 f          (25.6 MB)
  float* dis   = hB + (size_t)N * 64;              // N f
  int*   deg   = (int*)(dis + N);                  // N int
  int*   offs  = deg + N;                          // N+1 int
  int*   cur   = offs + N + 1;                     // N int
  int*   bsum  = cur + N;                          // 128 int
  float* psum  = (float*)(bsum + 128);             // NGRAPHS*64 f
  float* pcnt  = psum + NGRAPHS * 64;              // NGRAPHS f

  // ---- CSR build ----
  hipMemsetAsync(deg, 0, (size_t)N * sizeof(int), stream);
  hipMemsetAsync(cur, 0, (size_t)N * sizeof(int), stream);
  hist_kernel<<<2048, 256, 0, stream>>>(dst, deg, E);
  scan1_kernel<<<nb, 256, 0, stream>>>(deg, bsum, N);
  scan2_kernel<<<1, 64, 0, stream>>>(bsum, nb);
  scan3_kernel<<<nb, 256, 0, stream>>>(deg, bsum, offs, dis, N);
  fill_kernel<<<2048, 256, 0, stream>>>(src, dst, dis, offs, cur, edata, E);

  // ---- conv1: xw = x@W1 ; gather(relu) ----
  gemm_k<128><<<(N + 15) / 16, 256, 0, stream>>>(x, W1, xwA, N);
  gather_kernel<false><<<(N + 3) / 4, 256, 0, stream>>>(edata, offs, dis, xwA, b1,
                                                        batch, hB, psum, pcnt, N);

  // ---- conv2: xw = h@W2 ; gather + pool ----
  gemm_k<64><<<(N + 15) / 16, 256, 0, stream>>>(hB, W2, xwA, N);
  hipMemsetAsync(psum, 0, (NGRAPHS * 64 + NGRAPHS) * sizeof(float), stream);
  gather_kernel<true><<<(N + 3) / 4, 256, 0, stream>>>(edata, offs, dis, xwA, b2,
                                                       batch, hB, psum, pcnt, N);

  // ---- MLP head ----
  mlp_kernel<<<NGRAPHS, 64, 0, stream>>>(psum, pcnt, Wf1, bf1, Wf2, bf2, out);
}

// Round 4
// 1126.653 us; speedup vs baseline: 1.8386x; 1.1844x over previous
//
#include <hip/hip_runtime.h>
#include <hip/hip_bf16.h>

// GNN classifier: 2x GCNConv + global_mean_pool + 2-layer MLP.
// R2 (resubmitted after GPU acquisition timeout): gather conv with 8-wide edge
// unroll (4x int4 edata loads -> 8 independent xw row gathers in flight) to
// break the per-edge dependent-load latency chain.

#define NGRAPHS 256

// ---------------- histogram of dst ----------------
__global__ __launch_bounds__(256) void hist_kernel(const int* __restrict__ dst,
                                                   int* __restrict__ deg, int E) {
  int stride = gridDim.x * 256;
  for (int e = blockIdx.x * 256 + threadIdx.x; e < E; e += stride)
    atomicAdd(&deg[dst[e]], 1);
}

// ---------------- scan stage 1: per-1024-block sums ----------------
__global__ __launch_bounds__(256) void scan1_kernel(const int* __restrict__ deg,
                                                    int* __restrict__ bsum, int N) {
  __shared__ int red[4];
  int t = threadIdx.x;
  int base = blockIdx.x * 1024;
  int s = 0;
  for (int i = t; i < 1024; i += 256) {
    int idx = base + i;
    if (idx < N) s += deg[idx];
  }
#pragma unroll
  for (int o = 32; o > 0; o >>= 1) s += __shfl_down(s, o);
  if ((t & 63) == 0) red[t >> 6] = s;
  __syncthreads();
  if (t == 0) bsum[blockIdx.x] = red[0] + red[1] + red[2] + red[3];
}

// ---------------- scan stage 2: exclusive scan of <=128 block sums ----------------
__global__ __launch_bounds__(64) void scan2_kernel(int* __restrict__ bsum, int nb) {
  int lane = threadIdx.x;
  int v0 = lane < nb ? bsum[lane] : 0;
  int v1 = (64 + lane) < nb ? bsum[64 + lane] : 0;
  int x0 = v0, x1 = v1;
#pragma unroll
  for (int o = 1; o < 64; o <<= 1) {
    int y = __shfl_up(x0, o);
    if (lane >= o) x0 += y;
  }
#pragma unroll
  for (int o = 1; o < 64; o <<= 1) {
    int y = __shfl_up(x1, o);
    if (lane >= o) x1 += y;
  }
  int tot0 = __shfl(x0, 63);
  if (lane < nb) bsum[lane] = x0 - v0;
  if ((64 + lane) < nb) bsum[64 + lane] = tot0 + x1 - v1;
}

// ---------------- scan stage 3: per-element exclusive offsets + dis ----------------
__global__ __launch_bounds__(256) void scan3_kernel(const int* __restrict__ deg,
                                                    const int* __restrict__ bsum,
                                                    int* __restrict__ offs,
                                                    float* __restrict__ dis, int N) {
  __shared__ int wtot[4];
  int t = threadIdx.x, lane = t & 63, w = t >> 6;
  int base = blockIdx.x * 1024 + t * 4;
  int d0 = (base + 0) < N ? deg[base + 0] : 0;
  int d1 = (base + 1) < N ? deg[base + 1] : 0;
  int d2 = (base + 2) < N ? deg[base + 2] : 0;
  int d3 = (base + 3) < N ? deg[base + 3] : 0;
  int ts = d0 + d1 + d2 + d3;
  int x = ts;
#pragma unroll
  for (int o = 1; o < 64; o <<= 1) {
    int y = __shfl_up(x, o);
    if (lane >= o) x += y;
  }
  if (lane == 63) wtot[w] = x;
  __syncthreads();
  int woff = 0;
  for (int i = 0; i < w; ++i) woff += wtot[i];
  int o0 = bsum[blockIdx.x] + woff + (x - ts);
  int o1 = o0 + d0, o2 = o1 + d1, o3 = o2 + d2;
  if (base + 0 < N) { offs[base + 0] = o0; dis[base + 0] = rsqrtf((float)(d0 + 1)); }
  if (base + 1 < N) { offs[base + 1] = o1; dis[base + 1] = rsqrtf((float)(d1 + 1)); }
  if (base + 2 < N) { offs[base + 2] = o2; dis[base + 2] = rsqrtf((float)(d2 + 1)); }
  if (base + 3 < N) { offs[base + 3] = o3; dis[base + 3] = rsqrtf((float)(d3 + 1)); }
  if (base + 0 == N - 1) offs[N] = o0 + d0;
  if (base + 1 == N - 1) offs[N] = o1 + d1;
  if (base + 2 == N - 1) offs[N] = o2 + d2;
  if (base + 3 == N - 1) offs[N] = o3 + d3;
}

// ---------------- fill: edata[pos] = (src, norm) grouped by dst ----------------
__global__ __launch_bounds__(256) void fill_kernel(const int* __restrict__ src,
                                                   const int* __restrict__ dst,
                                                   const float* __restrict__ dis,
                                                   const int* __restrict__ offs,
                                                   int* __restrict__ cur,
                                                   int2* __restrict__ edata, int E) {
  int stride = gridDim.x * 256;
  for (int e = blockIdx.x * 256 + threadIdx.x; e < E; e += stride) {
    int s = src[e];
    int d = dst[e];
    float nm = dis[s] * dis[d];
    int pos = offs[d] + atomicAdd(&cur[d], 1);
    edata[pos] = make_int2(s, __float_as_int(nm));
  }
}

// ---------------- dense GEMM: Y[n,64] = X[n,K] @ W[K,64] ----------------
template <int K>
__global__ __launch_bounds__(256) void gemm_k(const float* __restrict__ X,
                                              const float* __restrict__ W,
                                              float* __restrict__ Y, int nrows) {
  __shared__ float ws[K][64];
  __shared__ float xs[16][K];
  int t = threadIdx.x;

  const float4* W4 = (const float4*)W;
  float4* ws4 = (float4*)(&ws[0][0]);
  constexpr int WV = K * 64 / 4;
  for (int i = t; i < WV; i += 256) ws4[i] = W4[i];

  int row0 = blockIdx.x * 16;
  int nr = min(16, nrows - row0);
  const float4* X4 = (const float4*)(X + (size_t)row0 * K);
  float4* xs4 = (float4*)(&xs[0][0]);
  for (int i = t; i < nr * K / 4; i += 256) xs4[i] = X4[i];
  __syncthreads();

  int wave = t >> 6, lane = t & 63;
  for (int r = wave; r < nr; r += 4) {
    float acc = 0.f;
#pragma unroll
    for (int k = 0; k < K; k += 4) {
      acc += xs[r][k + 0] * ws[k + 0][lane];
      acc += xs[r][k + 1] * ws[k + 1][lane];
      acc += xs[r][k + 2] * ws[k + 2][lane];
      acc += xs[r][k + 3] * ws[k + 3][lane];
    }
    Y[(size_t)(row0 + r) * 64 + lane] = acc;
  }
}

// ---------------- gather conv: one wave per dst node, 8-wide edge unroll ----
// acc = sum_{e in CSR[n]} norm_e * xw[src_e] + dis[n]^2 * xw[n] + bias
template <bool POOL>
__global__ __launch_bounds__(256) void gather_kernel(const int2* __restrict__ edata,
                                                     const int* __restrict__ offs,
                                                     const float* __restrict__ dis,
                                                     const float* __restrict__ xw,
                                                     const float* __restrict__ bias,
                                                     const int* __restrict__ batch,
                                                     float* __restrict__ outbuf,
                                                     float* __restrict__ psum,
                                                     float* __restrict__ pcnt, int N) {
  int lane = threadIdx.x & 63;
  int node = blockIdx.x * 4 + (threadIdx.x >> 6);
  if (node >= N) return;
  int beg = offs[node], end = offs[node + 1];
  float di = dis[node];
  float acc = di * di * xw[(size_t)node * 64 + lane];

  int j = beg;
  // align to even index so int4 (16B) loads of edata are legal
  if ((j & 1) && j < end) {
    int2 ed = edata[j];
    acc = fmaf(__int_as_float(ed.y), xw[(size_t)ed.x * 64 + lane], acc);
    ++j;
  }
  int ngroups = (end - j) >> 3;  // groups of 8 edges
  const int4* ed4 = (const int4*)(edata + j);
  for (int g = 0; g < ngroups; ++g) {
    int4 p0 = ed4[0];  // edges j+0, j+1  (x=src0,y=nm0,z=src1,w=nm1)
    int4 p1 = ed4[1];
    int4 p2 = ed4[2];
    int4 p3 = ed4[3];
    ed4 += 4;
    // 8 independent row gathers in flight
    float v0 = xw[(size_t)p0.x * 64 + lane];
    float v1 = xw[(size_t)p0.z * 64 + lane];
    float v2 = xw[(size_t)p1.x * 64 + lane];
    float v3 = xw[(size_t)p1.z * 64 + lane];
    float v4 = xw[(size_t)p2.x * 64 + lane];
    float v5 = xw[(size_t)p2.z * 64 + lane];
    float v6 = xw[(size_t)p3.x * 64 + lane];
    float v7 = xw[(size_t)p3.z * 64 + lane];
    acc = fmaf(__int_as_float(p0.y), v0, acc);
    acc = fmaf(__int_as_float(p0.w), v1, acc);
    acc = fmaf(__int_as_float(p1.y), v2, acc);
    acc = fmaf(__int_as_float(p1.w), v3, acc);
    acc = fmaf(__int_as_float(p2.y), v4, acc);
    acc = fmaf(__int_as_float(p2.w), v5, acc);
    acc = fmaf(__int_as_float(p3.y), v6, acc);
    acc = fmaf(__int_as_float(p3.w), v7, acc);
  }
  j += ngroups * 8;
  for (; j < end; ++j) {
    int2 ed = edata[j];
    acc = fmaf(__int_as_float(ed.y), xw[(size_t)ed.x * 64 + lane], acc);
  }

  acc += bias[lane];
  if (POOL) {
    int g = batch[node];
    atomicAdd(&psum[g * 64 + lane], acc);
    if (lane == 0) atomicAdd(&pcnt[g], 1.0f);
  } else {
    outbuf[(size_t)node * 64 + lane] = fmaxf(acc, 0.f);
  }
}

// ---------------- per-graph MLP ----------------
__global__ __launch_bounds__(64) void mlp_kernel(const float* __restrict__ psum,
                                                 const float* __restrict__ pcnt,
                                                 const float* __restrict__ Wf1,
                                                 const float* __restrict__ bf1,
                                                 const float* __restrict__ Wf2,
                                                 const float* __restrict__ bf2,
                                                 float* __restrict__ out) {
  int g = blockIdx.x;
  int lane = threadIdx.x;
  __shared__ float p[64];
  __shared__ float hh[32];
  float cnt = fmaxf(pcnt[g], 1.f);
  p[lane] = psum[g * 64 + lane] / cnt;
  __syncthreads();
  if (lane < 32) {
    float a = bf1[lane];
#pragma unroll
    for (int f = 0; f < 64; ++f) a += p[f] * Wf1[f * 32 + lane];
    hh[lane] = fmaxf(a, 0.f);
  }
  __syncthreads();
  if (lane < 8) {
    float a = bf2[lane];
#pragma unroll
    for (int j = 0; j < 32; ++j) a += hh[j] * Wf2[j * 8 + lane];
    out[g * 8 + lane] = a;
  }
}

extern "C" void kernel_launch(void* const* d_in, const int* in_sizes, int n_in,
                              void* d_out, int out_size, void* d_ws, size_t ws_size,
                              hipStream_t stream) {
  const float* x     = (const float*)d_in[0];
  const int*   ei    = (const int*)d_in[1];  // int64 in source -> int32 on device (JAX x64 off)
  const int*   batch = (const int*)d_in[2];
  const float* W1  = (const float*)d_in[3];
  const float* b1  = (const float*)d_in[4];
  const float* W2  = (const float*)d_in[5];
  const float* b2  = (const float*)d_in[6];
  const float* Wf1 = (const float*)d_in[7];
  const float* bf1 = (const float*)d_in[8];
  const float* Wf2 = (const float*)d_in[9];
  const float* bf2 = (const float*)d_in[10];
  float* out = (float*)d_out;

  const int N = in_sizes[0] / 128;  // 100000
  const int E = in_sizes[1] / 2;    // 3200000
  const int* src = ei;
  const int* dst = ei + E;
  const int nb = (N + 1023) / 1024;  // scan blocks (98)

  // workspace layout (edata first: d_ws is 256B aligned -> int4 loads legal)
  int2*  edata = (int2*)d_ws;                      // E int2          (25.6 MB)
  float* xwA   = (float*)(edata + E);              // N*64 f          (25.6 MB)
  float* hB    = xwA + (size_t)N * 64;             // N*64 f          (25.6 MB)
  float* dis   = hB + (size_t)N * 64;              // N f
  int*   deg   = (int*)(dis + N);                  // N int
  int*   offs  = deg + N;                          // N+1 int
  int*   cur   = offs + N + 1;                     // N int
  int*   bsum  = cur + N;                          // 128 int
  float* psum  = (float*)(bsum + 128);             // NGRAPHS*64 f
  float* pcnt  = psum + NGRAPHS * 64;              // NGRAPHS f

  // ---- CSR build ----
  hipMemsetAsync(deg, 0, (size_t)N * sizeof(int), stream);
  hipMemsetAsync(cur, 0, (size_t)N * sizeof(int), stream);
  hist_kernel<<<2048, 256, 0, stream>>>(dst, deg, E);
  scan1_kernel<<<nb, 256, 0, stream>>>(deg, bsum, N);
  scan2_kernel<<<1, 64, 0, stream>>>(bsum, nb);
  scan3_kernel<<<nb, 256, 0, stream>>>(deg, bsum, offs, dis, N);
  fill_kernel<<<2048, 256, 0, stream>>>(src, dst, dis, offs, cur, edata, E);

  // ---- conv1: xw = x@W1 ; gather(relu) ----
  gemm_k<128><<<(N + 15) / 16, 256, 0, stream>>>(x, W1, xwA, N);
  gather_kernel<false><<<(N + 3) / 4, 256, 0, stream>>>(edata, offs, dis, xwA, b1,
                                                        batch, hB, psum, pcnt, N);

  // ---- conv2: xw = h@W2 ; gather + pool ----
  gemm_k<64><<<(N + 15) / 16, 256, 0, stream>>>(hB, W2, xwA, N);
  hipMemsetAsync(psum, 0, (NGRAPHS * 64 + NGRAPHS) * sizeof(float), stream);
  gather_kernel<true><<<(N + 3) / 4, 256, 0, stream>>>(edata, offs, dis, xwA, b2,
                                                       batch, hB, psum, pcnt, N);

  // ---- MLP head ----
  mlp_kernel<<<NGRAPHS, 64, 0, stream>>>(psum, pcnt, Wf1, bf1, Wf2, bf2, out);
}

// Round 5
// 1058.956 us; speedup vs baseline: 1.9562x; 1.0639x over previous
//
#include <hip/hip_runtime.h>
#include <hip/hip_bf16.h>

// GNN classifier: 2x GCNConv + global_mean_pool + 2-layer MLP.
// R4: byte-diet for the gather.
//  - norm folding: xw'[s] = dis[s]*(x@W)[s] in GEMM epilogue; gather does
//    out = dis[d]*(sum_e xw'[src_e] + xw'[d]) + b  -> edata is src-only (4B/edge)
//  - xw' stored bf16 (128B/row); one 256B wave load fetches TWO rows
//    (lanes 0-31 even edge, lanes 32-63 odd edge, bf16x2 per lane)

#define NGRAPHS 256

__device__ __forceinline__ float bflo(unsigned u) { return __uint_as_float(u << 16); }
__device__ __forceinline__ float bfhi(unsigned u) { return __uint_as_float(u & 0xffff0000u); }
__device__ __forceinline__ unsigned short bfpack1(float v) {
  unsigned ua = __float_as_uint(v);
  ua += 0x7fffu + ((ua >> 16) & 1u);  // RNE
  return (unsigned short)(ua >> 16);
}
__device__ __forceinline__ unsigned bfpack2(float a, float b) {
  unsigned ua = __float_as_uint(a), ub = __float_as_uint(b);
  ua += 0x7fffu + ((ua >> 16) & 1u);
  ub += 0x7fffu + ((ub >> 16) & 1u);
  return (ua >> 16) | (ub & 0xffff0000u);
}

// ---------------- histogram of dst ----------------
__global__ __launch_bounds__(256) void hist_kernel(const int* __restrict__ dst,
                                                   int* __restrict__ deg, int E) {
  int stride = gridDim.x * 256;
  for (int e = blockIdx.x * 256 + threadIdx.x; e < E; e += stride)
    atomicAdd(&deg[dst[e]], 1);
}

// ---------------- scan stage 1 ----------------
__global__ __launch_bounds__(256) void scan1_kernel(const int* __restrict__ deg,
                                                    int* __restrict__ bsum, int N) {
  __shared__ int red[4];
  int t = threadIdx.x;
  int base = blockIdx.x * 1024;
  int s = 0;
  for (int i = t; i < 1024; i += 256) {
    int idx = base + i;
    if (idx < N) s += deg[idx];
  }
#pragma unroll
  for (int o = 32; o > 0; o >>= 1) s += __shfl_down(s, o);
  if ((t & 63) == 0) red[t >> 6] = s;
  __syncthreads();
  if (t == 0) bsum[blockIdx.x] = red[0] + red[1] + red[2] + red[3];
}

// ---------------- scan stage 2 ----------------
__global__ __launch_bounds__(64) void scan2_kernel(int* __restrict__ bsum, int nb) {
  int lane = threadIdx.x;
  int v0 = lane < nb ? bsum[lane] : 0;
  int v1 = (64 + lane) < nb ? bsum[64 + lane] : 0;
  int x0 = v0, x1 = v1;
#pragma unroll
  for (int o = 1; o < 64; o <<= 1) {
    int y = __shfl_up(x0, o);
    if (lane >= o) x0 += y;
  }
#pragma unroll
  for (int o = 1; o < 64; o <<= 1) {
    int y = __shfl_up(x1, o);
    if (lane >= o) x1 += y;
  }
  int tot0 = __shfl(x0, 63);
  if (lane < nb) bsum[lane] = x0 - v0;
  if ((64 + lane) < nb) bsum[64 + lane] = tot0 + x1 - v1;
}

// ---------------- scan stage 3: offsets + dis ----------------
__global__ __launch_bounds__(256) void scan3_kernel(const int* __restrict__ deg,
                                                    const int* __restrict__ bsum,
                                                    int* __restrict__ offs,
                                                    float* __restrict__ dis, int N) {
  __shared__ int wtot[4];
  int t = threadIdx.x, lane = t & 63, w = t >> 6;
  int base = blockIdx.x * 1024 + t * 4;
  int d0 = (base + 0) < N ? deg[base + 0] : 0;
  int d1 = (base + 1) < N ? deg[base + 1] : 0;
  int d2 = (base + 2) < N ? deg[base + 2] : 0;
  int d3 = (base + 3) < N ? deg[base + 3] : 0;
  int ts = d0 + d1 + d2 + d3;
  int x = ts;
#pragma unroll
  for (int o = 1; o < 64; o <<= 1) {
    int y = __shfl_up(x, o);
    if (lane >= o) x += y;
  }
  if (lane == 63) wtot[w] = x;
  __syncthreads();
  int woff = 0;
  for (int i = 0; i < w; ++i) woff += wtot[i];
  int o0 = bsum[blockIdx.x] + woff + (x - ts);
  int o1 = o0 + d0, o2 = o1 + d1, o3 = o2 + d2;
  if (base + 0 < N) { offs[base + 0] = o0; dis[base + 0] = rsqrtf((float)(d0 + 1)); }
  if (base + 1 < N) { offs[base + 1] = o1; dis[base + 1] = rsqrtf((float)(d1 + 1)); }
  if (base + 2 < N) { offs[base + 2] = o2; dis[base + 2] = rsqrtf((float)(d2 + 1)); }
  if (base + 3 < N) { offs[base + 3] = o3; dis[base + 3] = rsqrtf((float)(d3 + 1)); }
  if (base + 0 == N - 1) offs[N] = o0 + d0;
  if (base + 1 == N - 1) offs[N] = o1 + d1;
  if (base + 2 == N - 1) offs[N] = o2 + d2;
  if (base + 3 == N - 1) offs[N] = o3 + d3;
}

// ---------------- fill: edata[pos] = src, grouped by dst ----------------
__global__ __launch_bounds__(256) void fill_kernel(const int* __restrict__ src,
                                                   const int* __restrict__ dst,
                                                   const int* __restrict__ offs,
                                                   int* __restrict__ cur,
                                                   int* __restrict__ edata, int E) {
  int stride = gridDim.x * 256;
  for (int e = blockIdx.x * 256 + threadIdx.x; e < E; e += stride) {
    int d = dst[e];
    int pos = offs[d] + atomicAdd(&cur[d], 1);
    edata[pos] = src[e];
  }
}

// ---------------- gemm1: Y[n,64] = bf16( dis[n] * (X[n,128] @ W) ) ----------------
__global__ __launch_bounds__(256) void gemm1_kernel(const float* __restrict__ X,
                                                    const float* __restrict__ W,
                                                    const float* __restrict__ dis,
                                                    unsigned short* __restrict__ Y,
                                                    int nrows) {
  __shared__ float ws[128][64];
  __shared__ float xs[16][128];
  int t = threadIdx.x;

  const float4* W4 = (const float4*)W;
  float4* ws4 = (float4*)(&ws[0][0]);
  for (int i = t; i < 128 * 64 / 4; i += 256) ws4[i] = W4[i];

  int row0 = blockIdx.x * 16;
  int nr = min(16, nrows - row0);
  const float4* X4 = (const float4*)(X + (size_t)row0 * 128);
  float4* xs4 = (float4*)(&xs[0][0]);
  for (int i = t; i < nr * 128 / 4; i += 256) xs4[i] = X4[i];
  __syncthreads();

  int wave = t >> 6, lane = t & 63;
  for (int r = wave; r < nr; r += 4) {
    float acc = 0.f;
#pragma unroll
    for (int k = 0; k < 128; k += 4) {
      acc += xs[r][k + 0] * ws[k + 0][lane];
      acc += xs[r][k + 1] * ws[k + 1][lane];
      acc += xs[r][k + 2] * ws[k + 2][lane];
      acc += xs[r][k + 3] * ws[k + 3][lane];
    }
    Y[(size_t)(row0 + r) * 64 + lane] = bfpack1(acc * dis[row0 + r]);
  }
}

// ---------------- gemm2: Y[n,64] = bf16( dis[n] * (Xbf16[n,64] @ W) ) ----------------
__global__ __launch_bounds__(256) void gemm2_kernel(const unsigned* __restrict__ X32,
                                                    const float* __restrict__ W,
                                                    const float* __restrict__ dis,
                                                    unsigned short* __restrict__ Y,
                                                    int nrows) {
  __shared__ float ws[64][64];
  __shared__ unsigned xs[16][32];
  int t = threadIdx.x;

  const float4* W4 = (const float4*)W;
  float4* ws4 = (float4*)(&ws[0][0]);
  for (int i = t; i < 64 * 64 / 4; i += 256) ws4[i] = W4[i];

  int row0 = blockIdx.x * 16;
  int nr = min(16, nrows - row0);
  const uint4* X4 = (const uint4*)(X32 + (size_t)row0 * 32);
  uint4* xs4 = (uint4*)(&xs[0][0]);
  for (int i = t; i < nr * 32 / 4; i += 256) xs4[i] = X4[i];
  __syncthreads();

  int wave = t >> 6, lane = t & 63;
  for (int r = wave; r < nr; r += 4) {
    float acc = 0.f;
#pragma unroll
    for (int k2 = 0; k2 < 32; ++k2) {
      unsigned u = xs[r][k2];
      acc += bflo(u) * ws[2 * k2 + 0][lane];
      acc += bfhi(u) * ws[2 * k2 + 1][lane];
    }
    Y[(size_t)(row0 + r) * 64 + lane] = bfpack1(acc * dis[row0 + r]);
  }
}

// ---------------- gather conv: one wave per dst node, paired bf16 rows ----
// out = dis[d]*(sum_e xw'[src_e] + xw'[d]) + bias ; xw' rows are bf16 (32 uints)
template <bool POOL>
__global__ __launch_bounds__(256) void gather_kernel(const int* __restrict__ edata,
                                                     const int* __restrict__ offs,
                                                     const float* __restrict__ dis,
                                                     const unsigned* __restrict__ xw32,
                                                     const float* __restrict__ bias,
                                                     const int* __restrict__ batch,
                                                     unsigned* __restrict__ out32,
                                                     float* __restrict__ psum,
                                                     float* __restrict__ pcnt, int N) {
  int lane = threadIdx.x & 63;
  int half = lane >> 5;        // 0: even edge of pair, 1: odd edge
  int f2 = lane & 31;          // feature-pair index (features 2*f2, 2*f2+1)
  int node = blockIdx.x * 4 + (threadIdx.x >> 6);
  if (node >= N) return;
  int beg = offs[node], end = offs[node + 1];
  float acc0 = 0.f, acc1 = 0.f;

  int j = beg;
  // singles until edata index is 16B aligned
  for (; j < end && (j & 3); ++j) {
    unsigned u = xw32[edata[j] * 32 + f2];
    if (half == 0) { acc0 += bflo(u); acc1 += bfhi(u); }
  }
  // groups of 8 edges: 2x int4 index loads + 4 paired row loads (2 rows/VMEM)
  for (; j + 8 <= end; j += 8) {
    int4 a = *(const int4*)(edata + j);
    int4 b = *(const int4*)(edata + j + 4);
    int e0 = half ? a.y : a.x;
    int e1 = half ? a.w : a.z;
    int e2 = half ? b.y : b.x;
    int e3 = half ? b.w : b.z;
    unsigned u0 = xw32[e0 * 32 + f2];
    unsigned u1 = xw32[e1 * 32 + f2];
    unsigned u2 = xw32[e2 * 32 + f2];
    unsigned u3 = xw32[e3 * 32 + f2];
    acc0 += bflo(u0); acc1 += bfhi(u0);
    acc0 += bflo(u1); acc1 += bfhi(u1);
    acc0 += bflo(u2); acc1 += bfhi(u2);
    acc0 += bflo(u3); acc1 += bfhi(u3);
  }
  // tail singles
  for (; j < end; ++j) {
    unsigned u = xw32[edata[j] * 32 + f2];
    if (half == 0) { acc0 += bflo(u); acc1 += bfhi(u); }
  }

  // combine halves (each lane then holds the full edge sum for its 2 features)
  acc0 += __shfl_xor(acc0, 32);
  acc1 += __shfl_xor(acc1, 32);

  // self-loop + scale + bias
  unsigned us = xw32[node * 32 + f2];
  acc0 += bflo(us);
  acc1 += bfhi(us);
  float d = dis[node];
  acc0 = fmaf(d, acc0, bias[2 * f2 + 0]);
  acc1 = fmaf(d, acc1, bias[2 * f2 + 1]);

  if (POOL) {
    if (half == 0) {
      int g = batch[node];
      atomicAdd(&psum[g * 64 + 2 * f2 + 0], acc0);
      atomicAdd(&psum[g * 64 + 2 * f2 + 1], acc1);
      if (f2 == 0) atomicAdd(&pcnt[g], 1.0f);
    }
  } else {
    if (half == 0)
      out32[node * 32 + f2] = bfpack2(fmaxf(acc0, 0.f), fmaxf(acc1, 0.f));
  }
}

// ---------------- per-graph MLP ----------------
__global__ __launch_bounds__(64) void mlp_kernel(const float* __restrict__ psum,
                                                 const float* __restrict__ pcnt,
                                                 const float* __restrict__ Wf1,
                                                 const float* __restrict__ bf1,
                                                 const float* __restrict__ Wf2,
                                                 const float* __restrict__ bf2,
                                                 float* __restrict__ out) {
  int g = blockIdx.x;
  int lane = threadIdx.x;
  __shared__ float p[64];
  __shared__ float hh[32];
  float cnt = fmaxf(pcnt[g], 1.f);
  p[lane] = psum[g * 64 + lane] / cnt;
  __syncthreads();
  if (lane < 32) {
    float a = bf1[lane];
#pragma unroll
    for (int f = 0; f < 64; ++f) a += p[f] * Wf1[f * 32 + lane];
    hh[lane] = fmaxf(a, 0.f);
  }
  __syncthreads();
  if (lane < 8) {
    float a = bf2[lane];
#pragma unroll
    for (int j = 0; j < 32; ++j) a += hh[j] * Wf2[j * 8 + lane];
    out[g * 8 + lane] = a;
  }
}

extern "C" void kernel_launch(void* const* d_in, const int* in_sizes, int n_in,
                              void* d_out, int out_size, void* d_ws, size_t ws_size,
                              hipStream_t stream) {
  const float* x     = (const float*)d_in[0];
  const int*   ei    = (const int*)d_in[1];  // int64 in source -> int32 on device (JAX x64 off)
  const int*   batch = (const int*)d_in[2];
  const float* W1  = (const float*)d_in[3];
  const float* b1  = (const float*)d_in[4];
  const float* W2  = (const float*)d_in[5];
  const float* b2  = (const float*)d_in[6];
  const float* Wf1 = (const float*)d_in[7];
  const float* bf1 = (const float*)d_in[8];
  const float* Wf2 = (const float*)d_in[9];
  const float* bf2 = (const float*)d_in[10];
  float* out = (float*)d_out;

  const int N = in_sizes[0] / 128;  // 100000
  const int E = in_sizes[1] / 2;    // 3200000
  const int* src = ei;
  const int* dst = ei + E;
  const int nb = (N + 1023) / 1024;  // scan blocks (98)

  // workspace layout (d_ws is widely aligned; all segments keep 16B alignment)
  int*      edata = (int*)d_ws;                        // E int          (12.8 MB)
  unsigned* xwA   = (unsigned*)(edata + E);            // N*32 uint (bf16x2) 12.8 MB
  unsigned* hB    = xwA + (size_t)N * 32;              // N*32 uint (bf16x2) 12.8 MB
  float*    dis   = (float*)(hB + (size_t)N * 32);     // N f
  int*      deg   = (int*)(dis + N);                   // N int
  int*      offs  = deg + N;                           // N+1 int
  int*      cur   = offs + N + 1;                      // N int
  int*      bsum  = cur + N;                           // 128 int
  float*    psum  = (float*)(bsum + 128);              // NGRAPHS*64 f
  float*    pcnt  = psum + NGRAPHS * 64;               // NGRAPHS f

  // ---- CSR build ----
  hipMemsetAsync(deg, 0, (size_t)N * sizeof(int), stream);
  hipMemsetAsync(cur, 0, (size_t)N * sizeof(int), stream);
  hist_kernel<<<2048, 256, 0, stream>>>(dst, deg, E);
  scan1_kernel<<<nb, 256, 0, stream>>>(deg, bsum, N);
  scan2_kernel<<<1, 64, 0, stream>>>(bsum, nb);
  scan3_kernel<<<nb, 256, 0, stream>>>(deg, bsum, offs, dis, N);
  fill_kernel<<<2048, 256, 0, stream>>>(src, dst, offs, cur, edata, E);

  // ---- conv1: xw' = bf16(dis * x@W1) ; gather(relu) -> hB (bf16) ----
  gemm1_kernel<<<(N + 15) / 16, 256, 0, stream>>>(x, W1, dis, (unsigned short*)xwA, N);
  gather_kernel<false><<<(N + 3) / 4, 256, 0, stream>>>(edata, offs, dis, xwA, b1,
                                                        batch, hB, psum, pcnt, N);

  // ---- conv2: xw' = bf16(dis * h@W2) ; gather + pool ----
  gemm2_kernel<<<(N + 15) / 16, 256, 0, stream>>>(hB, W2, dis, (unsigned short*)xwA, N);
  hipMemsetAsync(psum, 0, (NGRAPHS * 64 + NGRAPHS) * sizeof(float), stream);
  gather_kernel<true><<<(N + 3) / 4, 256, 0, stream>>>(edata, offs, dis, xwA, b2,
                                                       batch, hB, psum, pcnt, N);

  // ---- MLP head ----
  mlp_kernel<<<NGRAPHS, 64, 0, stream>>>(psum, pcnt, Wf1, bf1, Wf2, bf2, out);
}